// Round 14
// baseline (697.785 us; speedup 1.0000x reference)
//
#include <hip/hip_runtime.h>

// Problem constants
#define B_    32
#define T_    512
#define TT    (T_ * T_)        // 262144
#define NCELL (B_ * TT)        // 8388608
#define NBINS 256              // bin = floor(u*256): pow-2 scale, exact in fp32
#define CAP   8192
#define NBLK  512              // 2 blocks/CU guaranteed by __launch_bounds__(256,2)

// Workspace layout (bytes)
#define OFF_HIST   0                            // int hist[2][32][256] = 64 KiB
#define OFF_NFG    (2 * B_ * NBINS * 4)         // float nfg_sum[32]     @65536
#define OFF_GCNT   (OFF_NFG + B_ * 4)           // int gcnt[64]          @65664
#define OFF_BAR    (OFF_GCNT + 64 * 4)          // int {cnt,gen}         @65920
#define ZERO_BYTES (OFF_BAR + 8)                // 65928
#define OFF_GBUF   (1u * 1024 * 1024)           // u64 gbuf[64][CAP] = 4 MiB

// Manual grid barrier: generation-counted, device-scope atomics.
// Requires all NBLK blocks co-resident (guaranteed: 512 blocks, >=2/CU).
// __threadfence() on gfx95x emits the L2 writeback/invalidate needed for
// cross-XCD visibility of the plain loads/stores around the barrier.
__device__ __forceinline__ void grid_barrier(int* cnt, int* gen) {
    __syncthreads();
    if (threadIdx.x == 0) {
        __threadfence();   // release: make prior writes visible device-wide
        int g = __hip_atomic_load(gen, __ATOMIC_RELAXED, __HIP_MEMORY_SCOPE_AGENT);
        int a = __hip_atomic_fetch_add(cnt, 1, __ATOMIC_ACQ_REL, __HIP_MEMORY_SCOPE_AGENT);
        if (a == NBLK - 1) {
            __hip_atomic_store(cnt, 0, __ATOMIC_RELAXED, __HIP_MEMORY_SCOPE_AGENT);
            __hip_atomic_fetch_add(gen, 1, __ATOMIC_RELEASE, __HIP_MEMORY_SCOPE_AGENT);
        } else {
            while (__hip_atomic_load(gen, __ATOMIC_ACQUIRE, __HIP_MEMORY_SCOPE_AGENT) == g)
                __builtin_amdgcn_s_sleep(8);
        }
        __threadfence();   // acquire: invalidate stale L1/L2 before reads
    }
    __syncthreads();
}

// Single fused kernel, 512 blocks x 256 threads. Block = 16384 cells of one
// batch (16 blocks/batch). Per-thread (flag|u_bits) state for its 64 cells
// lives in myrec[64] REGISTERS across all phases (statically indexed).
__global__ __launch_bounds__(256, 2) void fused(
    const float* __restrict__ gt, const float* __restrict__ alli,
    const float* __restrict__ ufg, const float* __restrict__ ubg,
    float* __restrict__ coords, float* __restrict__ posv,
    float* __restrict__ anchor, int* __restrict__ hist,
    float* __restrict__ nfg_sum, unsigned long long* __restrict__ gbuf,
    int* __restrict__ gcnt, int* __restrict__ bar)
{
    __shared__ int lh[2][NBINS];
    int tid = threadIdx.x;
    lh[0][tid] = 0;
    lh[1][tid] = 0;
    __syncthreads();

    int bid  = blockIdx.x;
    int b    = bid >> 4;                   // 16 blocks per batch
    int base = b * TT + (bid & 15) * 16384;

    unsigned myrec[64];                    // statically indexed everywhere
    float fgsum = 0.f;

    // ---- P1: stream inputs, classify, LDS hist, posv, coords ----
    #pragma unroll
    for (int it = 0; it < 16; ++it) {
        int i0 = base + it * 1024 + tid * 4;
        float4 gv = *reinterpret_cast<const float4*>(gt   + i0);
        float4 av = *reinterpret_cast<const float4*>(alli + i0);
        float4 fv = *reinterpret_cast<const float4*>(ufg  + i0);
        float4 bv = *reinterpret_cast<const float4*>(ubg  + i0);
        float4 pv;
        #pragma unroll
        for (int j = 0; j < 4; ++j) {
            float gtv = ((const float*)&gv)[j];
            float al  = ((const float*)&av)[j];
            bool  fgc   = (gtv > 0.5f);
            float fgval = fgc ? al : 0.f;
            fgsum += fgval;
            bool fg = fgval > 0.f;
            bool bg = (!fgc) && (al > 0.f);
            ((float*)&pv)[j] = (fgc && al >= 1.f) ? 1.f : 0.f;
            unsigned flag = fg ? 1u : (bg ? 2u : 0u);
            unsigned out  = 0u;
            if (flag) {
                float u = (flag == 1u) ? ((const float*)&fv)[j] : ((const float*)&bv)[j];
                unsigned ub = __float_as_uint(u);   // u in [0,1) -> fits 30 bits
                out = (flag << 30) | ub;
                int bin = (int)(u * 256.f);         // exact pow2 scale
                bin = bin > (NBINS - 1) ? (NBINS - 1) : bin;
                atomicAdd(&lh[flag - 1][bin], 1);
            }
            myrec[it * 4 + j] = out;
        }
        *reinterpret_cast<float4*>(posv + i0) = pv;
    }
    __syncthreads();

    // flush block-local histogram
    int v0 = lh[0][tid];
    if (v0) atomicAdd(hist + b * NBINS + tid, v0);
    int v1 = lh[1][tid];
    if (v1) atomicAdd(hist + (B_ + b) * NBINS + tid, v1);

    // fg-mask value sum
    for (int off = 32; off; off >>= 1) fgsum += __shfl_down(fgsum, off);
    __shared__ float red[4];
    int lane = tid & 63, w = tid >> 6;
    if (lane == 0) red[w] = fgsum;
    __syncthreads();
    if (tid == 0) {
        float t = red[0] + red[1] + red[2] + red[3];
        if (t != 0.f) atomicAdd(nfg_sum + b, t);
    }

    // coords: grid-strided contiguous float4 stripes (fully coalesced)
    unsigned g = (unsigned)bid * 256u + (unsigned)tid;   // 131072 threads
    for (int k = 0; k < 48; ++k) {                       // 48*131072 float4s
        unsigned q  = (unsigned)k * 131072u + g;
        unsigned p0 = q * 4u;
        float4 o;
        #pragma unroll
        for (int j = 0; j < 4; ++j) {
            unsigned p  = p0 + (unsigned)j;
            unsigned i  = p / 3u;
            unsigned c  = p - i * 3u;
            unsigned ib = i >> 18;
            unsigned rm = i & (TT - 1);
            unsigned s  = rm & (T_ - 1);
            unsigned e  = (rm >> 9) + s + 1u;
            unsigned v  = (c == 0u) ? ib : ((c == 1u) ? s : e);
            ((float*)&o)[j] = (float)v;
        }
        reinterpret_cast<float4*>(coords)[q] = o;
    }

    grid_barrier(bar, bar + 1);    // hist + nfg_sum complete

    // ---- P2: per-block boundary bin + rank (redundant per batch, consistent) ----
    __shared__ int suf[256];
    __shared__ int sbb[2], srsel[2];
    #pragma unroll
    for (int which = 0; which < 2; ++which) {
        int mybin = hist[(which * B_ + b) * NBINS + tid];
        suf[tid] = mybin;
        __syncthreads();
        for (int off = 1; off < 256; off <<= 1) {
            int add = (tid + off < 256) ? suf[tid + off] : 0;
            __syncthreads();
            suf[tid] += add;
            __syncthreads();
        }
        int total = suf[0];
        int sel;
        if (which == 0) {
            sel = total < 256 ? total : 256;
        } else {
            float nfg = nfg_sum[b];
            float cl  = 1024.f - fminf(nfg, 256.f);
            int cnt = (cl <= 0.f) ? 0 : (int)ceilf(cl);
            cnt = cnt > 1024 ? 1024 : cnt;
            sel = cnt < total ? cnt : total;
        }
        if (tid == 0) {
            if (sel <= 0)          { sbb[which] = -1; srsel[which] = 0; }
            else if (sel >= total) { sbb[which] = -2; srsel[which] = 0; }
        }
        int cumAbove = suf[tid] - mybin;
        if (sel > 0 && sel < total && cumAbove < sel && suf[tid] >= sel) {
            sbb[which]   = tid;                  // unique boundary thread
            srsel[which] = sel - cumAbove;       // 1-based rank within bin
        }
        __syncthreads();
    }
    int bbf = sbb[0], bbb = sbb[1];

    // ---- P3: gather from registers, block-aggregated reservation ----
    __shared__ int lcnt[2], lpos[2], lbase[2];
    if (tid < 2) { lcnt[tid] = 0; lpos[tid] = 0; }
    __syncthreads();
    unsigned long long c0 = 0, c1 = 0;
    int w0 = 0, w1 = 0, mycnt = 0;
    #pragma unroll
    for (int k = 0; k < 64; ++k) {
        unsigned rv = myrec[k];
        unsigned flag = rv >> 30;
        if (!flag) continue;
        unsigned ub = rv & 0x3FFFFFFFu;
        float u = __uint_as_float(ub);
        int bin = (int)(u * 256.f);
        bin = bin > (NBINS - 1) ? (NBINS - 1) : bin;
        int ww = (int)flag - 1;
        if (bin == ((ww == 0) ? bbf : bbb)) {
            int idx = base + (k >> 2) * 1024 + tid * 4 + (k & 3);
            unsigned inb = (unsigned)(idx & (TT - 1));
            unsigned long long key =
                ((unsigned long long)ub << 32) | (0xFFFFFFFFu - inb);
            if (mycnt == 0)      { c0 = key; w0 = ww; mycnt = 1; atomicAdd(&lcnt[ww], 1); }
            else if (mycnt == 1) { c1 = key; w1 = ww; mycnt = 2; atomicAdd(&lcnt[ww], 1); }
            else {  // vanishingly rare overflow: direct global reservation
                int wb = ww * 32 + b;
                int pos = atomicAdd(gcnt + wb, 1);
                if (pos < CAP) gbuf[(size_t)wb * CAP + pos] = key;
            }
        }
    }
    __syncthreads();
    if (tid == 0) lbase[0] = lcnt[0] ? atomicAdd(gcnt + b, lcnt[0]) : 0;
    if (tid == 1) lbase[1] = lcnt[1] ? atomicAdd(gcnt + 32 + b, lcnt[1]) : 0;
    __syncthreads();
    if (mycnt >= 1) {
        int ofs = atomicAdd(&lpos[w0], 1);
        int p = lbase[w0] + ofs;
        if (p < CAP) gbuf[(size_t)(w0 * 32 + b) * CAP + p] = c0;
    }
    if (mycnt >= 2) {
        int ofs = atomicAdd(&lpos[w1], 1);
        int p = lbase[w1] + ofs;
        if (p < CAP) gbuf[(size_t)(w1 * 32 + b) * CAP + p] = c1;
    }

    grid_barrier(bar, bar + 1);    // all gathers complete

    // ---- P4: per-block exact r-th largest (redundant per batch) ----
    __shared__ unsigned long long sthr[2];
    #pragma unroll
    for (int which = 0; which < 2; ++which) {
        int bbv = (which == 0) ? bbf : bbb;
        if (bbv == -1)      { if (tid == 0) sthr[which] = ~0ULL; }
        else if (bbv == -2) { if (tid == 0) sthr[which] = 0ULL;  }
        else {
            int wb = which * 32 + b;
            int n = gcnt[wb]; n = n > CAP ? CAP : n;
            int r = srsel[which];
            const unsigned long long* buf = gbuf + (size_t)wb * CAP;
            for (int i = tid; i < n; i += 256) {
                unsigned long long kk = buf[i];
                int rank = 0;
                for (int j2 = 0; j2 < n; ++j2) rank += (buf[j2] > kk) ? 1 : 0;
                if (rank == r - 1) sthr[which] = kk;  // unique writer
            }
        }
    }
    __syncthreads();
    unsigned long long tf = sthr[0], tb2 = sthr[1];

    // ---- P5: anchor from registers ----
    #pragma unroll
    for (int it = 0; it < 16; ++it) {
        int i0 = base + it * 1024 + tid * 4;
        float4 o;
        #pragma unroll
        for (int j = 0; j < 4; ++j) {
            unsigned rv = myrec[it * 4 + j];
            unsigned flag = rv >> 30;
            float v = 0.f;
            if (flag) {
                unsigned ub  = rv & 0x3FFFFFFFu;
                unsigned inb = (unsigned)((i0 + j) & (TT - 1));
                unsigned long long key =
                    ((unsigned long long)ub << 32) | (0xFFFFFFFFu - inb);
                v = (key >= ((flag == 1u) ? tf : tb2)) ? 1.f : 0.f;
            }
            ((float*)&o)[j] = v;
        }
        *reinterpret_cast<float4*>(anchor + i0) = o;
    }
}

extern "C" void kernel_launch(void* const* d_in, const int* in_sizes, int n_in,
                              void* d_out, int out_size, void* d_ws, size_t ws_size,
                              hipStream_t stream)
{
    const float* gt   = (const float*)d_in[0];
    const float* alli = (const float*)d_in[1];
    const float* ufg  = (const float*)d_in[2];
    const float* ubg  = (const float*)d_in[3];

    char* ws = (char*)d_ws;
    int*                 hist = (int*)(ws + OFF_HIST);
    float*               nfg  = (float*)(ws + OFF_NFG);
    int*                 gcnt = (int*)(ws + OFF_GCNT);
    int*                 bar  = (int*)(ws + OFF_BAR);
    unsigned long long*  gbuf = (unsigned long long*)(ws + OFF_GBUF);

    float* coords  = (float*)d_out;
    float* anchorF = coords + (size_t)3 * NCELL;
    float* posv    = anchorF + NCELL;

    hipMemsetAsync(d_ws, 0, ZERO_BYTES, stream);

    fused<<<dim3(NBLK), dim3(256), 0, stream>>>(
        gt, alli, ufg, ubg, coords, posv, anchorF, hist, nfg, gbuf, gcnt, bar);
}

// Round 15
// 373.209 us; speedup vs baseline: 1.8697x; 1.8697x over previous
//
#include <hip/hip_runtime.h>

// Problem constants
#define B_    32
#define T_    512
#define TT    (T_ * T_)        // 262144
#define NCELL (B_ * TT)        // 8388608
#define NBINS 256              // bin = floor(u*256): pow-2 scale, exact in fp32
#define CAP   8192

// Workspace layout (bytes)
#define OFF_HIST   0                            // int hist[2][32][256] = 64 KiB
#define OFF_NFG    (2 * B_ * NBINS * 4)         // float nfg_sum[32]  @65536
#define OFF_GCNT   (OFF_NFG + B_ * 4)           // int gcnt[64]       @65664
#define OFF_THR    (OFF_GCNT + 64 * 4)          // u64 thr[64]        @65920 (8-aligned)
#define ZERO_BYTES (OFF_THR + 64 * 8)           // 66432
#define OFF_GBUF   (1u * 1024 * 1024)           // u64 gbuf[64][CAP] = 4 MiB
// rec[NCELL] lives in d_out's anchor region: K1 writes, K3 reads,
// K5 reads + overwrites in place.

// K1: block = 8192 cells of one batch. Software-pipelined input loads
// (next iter's 4 float4s issued before processing current — R5 showed the
// compiler minimizes to 16 VGPRs and kills ILP without this; launch_bounds
// (256,4) gives it a 128-VGPR budget at >=50% occupancy). LDS-privatized
// histogram; coalesced pure-function coords stripe writer.
__global__ __launch_bounds__(256, 4) void k1_main(
    const float* __restrict__ gt, const float* __restrict__ alli,
    const float* __restrict__ ufg, const float* __restrict__ ubg,
    float* __restrict__ coords, float* __restrict__ posv,
    unsigned* __restrict__ rec, int* __restrict__ hist,
    float* __restrict__ nfg_sum)
{
    __shared__ int lh[2][NBINS];
    int tid = threadIdx.x;
    lh[0][tid] = 0;
    lh[1][tid] = 0;
    __syncthreads();

    int bid  = blockIdx.x;
    int b    = bid >> 5;                   // 32 blocks per batch
    int base = b * TT + (bid & 31) * 8192;

    float fgsum = 0.f;

    int i0 = base + tid * 4;
    float4 gv = *reinterpret_cast<const float4*>(gt   + i0);
    float4 av = *reinterpret_cast<const float4*>(alli + i0);
    float4 fv = *reinterpret_cast<const float4*>(ufg  + i0);
    float4 bv = *reinterpret_cast<const float4*>(ubg  + i0);

    #pragma unroll
    for (int it = 0; it < 8; ++it) {
        float4 gn, an, fn, bn;
        int i1 = i0 + 1024;
        if (it < 7) {                       // prefetch next iteration
            gn = *reinterpret_cast<const float4*>(gt   + i1);
            an = *reinterpret_cast<const float4*>(alli + i1);
            fn = *reinterpret_cast<const float4*>(ufg  + i1);
            bn = *reinterpret_cast<const float4*>(ubg  + i1);
        }
        float4 pv; uint4 rv;
        #pragma unroll
        for (int j = 0; j < 4; ++j) {
            float gtv = ((const float*)&gv)[j];
            float al  = ((const float*)&av)[j];
            bool  fgc   = (gtv > 0.5f);
            float fgval = fgc ? al : 0.f;
            fgsum += fgval;
            bool fg = fgval > 0.f;
            bool bg = (!fgc) && (al > 0.f);
            ((float*)&pv)[j] = (fgc && al >= 1.f) ? 1.f : 0.f;
            unsigned flag = fg ? 1u : (bg ? 2u : 0u);
            unsigned out  = 0u;
            if (flag) {
                float u = (flag == 1u) ? ((const float*)&fv)[j] : ((const float*)&bv)[j];
                unsigned ub = __float_as_uint(u);   // u in [0,1) -> fits 30 bits
                out = (flag << 30) | ub;
                int bin = (int)(u * 256.f);         // exact pow2 scale
                bin = bin > (NBINS - 1) ? (NBINS - 1) : bin;
                atomicAdd(&lh[flag - 1][bin], 1);
            }
            ((unsigned*)&rv)[j] = out;
        }
        *reinterpret_cast<float4*>(posv + i0) = pv;
        *reinterpret_cast<uint4*>(rec + i0)   = rv;
        if (it < 7) { gv = gn; av = an; fv = fn; bv = bn; i0 = i1; }
    }
    __syncthreads();

    // flush block-local histogram: <=512 global atomics per block
    int v0 = lh[0][tid];
    if (v0) atomicAdd(hist + b * NBINS + tid, v0);
    int v1 = lh[1][tid];
    if (v1) atomicAdd(hist + (B_ + b) * NBINS + tid, v1);

    // fg-mask value sum: wave reduce then block reduce, one atomic per block
    for (int off = 32; off; off >>= 1) fgsum += __shfl_down(fgsum, off);
    __shared__ float red[4];
    int lane = tid & 63, w = tid >> 6;
    if (lane == 0) red[w] = fgsum;
    __syncthreads();
    if (tid == 0) {
        float t = red[0] + red[1] + red[2] + red[3];
        if (t != 0.f) atomicAdd(nfg_sum + b, t);
    }

    // coords: grid-strided contiguous float4 stripes (fully coalesced)
    unsigned g = (unsigned)bid * 256u + (unsigned)tid;   // 262144 threads
    #pragma unroll
    for (int k = 0; k < 24; ++k) {                       // 24*262144 float4s
        unsigned q  = (unsigned)k * 262144u + g;
        unsigned p0 = q * 4u;
        float4 o;
        #pragma unroll
        for (int j = 0; j < 4; ++j) {
            unsigned p  = p0 + (unsigned)j;
            unsigned i  = p / 3u;                        // magic-mul div
            unsigned c  = p - i * 3u;
            unsigned ib = i >> 18;
            unsigned rm = i & (TT - 1);
            unsigned s  = rm & (T_ - 1);
            unsigned e  = (rm >> 9) + s + 1u;
            unsigned v  = (c == 0u) ? ib : ((c == 1u) ? s : e);
            ((float*)&o)[j] = (float)v;
        }
        reinterpret_cast<float4*>(coords)[q] = o;
    }
}

// K3: per-block redundant bounds scan (deterministic -> consistent across
// the 32 blocks of a batch; kills the k2 launch) + gather with
// block-aggregated reservation (R11: one returning global atomic per
// (block,which) instead of per candidate).
__global__ __launch_bounds__(256) void k3_gather(
    const unsigned* __restrict__ rec, const int* __restrict__ hist,
    const float* __restrict__ nfg_sum,
    unsigned long long* __restrict__ gbuf, int* __restrict__ gcnt)
{
    __shared__ int suf[256];
    __shared__ int sbb[2];
    int tid = threadIdx.x;
    int bid = blockIdx.x;
    int b   = bid >> 5;

    #pragma unroll
    for (int which = 0; which < 2; ++which) {
        int mybin = hist[(which * B_ + b) * NBINS + tid];
        suf[tid] = mybin;
        __syncthreads();
        for (int off = 1; off < 256; off <<= 1) {
            int add = (tid + off < 256) ? suf[tid + off] : 0;
            __syncthreads();
            suf[tid] += add;
            __syncthreads();
        }
        int total = suf[0];
        int sel;
        if (which == 0) {
            sel = total < 256 ? total : 256;
        } else {
            float nfg = nfg_sum[b];
            float cl  = 1024.f - fminf(nfg, 256.f);
            int cnt = (cl <= 0.f) ? 0 : (int)ceilf(cl);
            cnt = cnt > 1024 ? 1024 : cnt;
            sel = cnt < total ? cnt : total;
        }
        if (tid == 0) {
            if (sel <= 0)          sbb[which] = -1;
            else if (sel >= total) sbb[which] = -2;
        }
        int cumAbove = suf[tid] - mybin;
        if (sel > 0 && sel < total && cumAbove < sel && suf[tid] >= sel)
            sbb[which] = tid;                    // unique boundary thread
        __syncthreads();
    }
    int bbf = sbb[0], bbb = sbb[1];

    __shared__ int lcnt[2], lpos[2], lbase[2];
    if (tid < 2) { lcnt[tid] = 0; lpos[tid] = 0; }
    __syncthreads();

    int base = b * TT + (bid & 31) * 8192;
    unsigned long long c0 = 0, c1 = 0;
    int w0 = 0, w1 = 0, mycnt = 0;

    #pragma unroll
    for (int it = 0; it < 8; ++it) {
        int i0 = base + it * 1024 + tid * 4;
        uint4 r = *reinterpret_cast<const uint4*>(rec + i0);
        #pragma unroll
        for (int j = 0; j < 4; ++j) {
            unsigned rv = ((const unsigned*)&r)[j];
            unsigned flag = rv >> 30;
            if (!flag) continue;
            unsigned ub = rv & 0x3FFFFFFFu;
            float u = __uint_as_float(ub);
            int bin = (int)(u * 256.f);         // identical expr to K1
            bin = bin > (NBINS - 1) ? (NBINS - 1) : bin;
            int ww = (int)flag - 1;
            if (bin == ((ww == 0) ? bbf : bbb)) {
                unsigned inb = (unsigned)((i0 + j) & (TT - 1));
                unsigned long long key =
                    ((unsigned long long)ub << 32) | (0xFFFFFFFFu - inb);
                if (mycnt == 0)      { c0 = key; w0 = ww; mycnt = 1; atomicAdd(&lcnt[ww], 1); }
                else if (mycnt == 1) { c1 = key; w1 = ww; mycnt = 2; atomicAdd(&lcnt[ww], 1); }
                else {  // vanishingly rare overflow: direct reservation
                    int wb = ww * 32 + b;
                    int pos = atomicAdd(gcnt + wb, 1);
                    if (pos < CAP) gbuf[(size_t)wb * CAP + pos] = key;
                }
            }
        }
    }
    __syncthreads();
    if (tid == 0) lbase[0] = lcnt[0] ? atomicAdd(gcnt + b, lcnt[0]) : 0;
    if (tid == 1) lbase[1] = lcnt[1] ? atomicAdd(gcnt + 32 + b, lcnt[1]) : 0;
    __syncthreads();
    if (mycnt >= 1) {
        int ofs = atomicAdd(&lpos[w0], 1);
        int p = lbase[w0] + ofs;
        if (p < CAP) gbuf[(size_t)(w0 * 32 + b) * CAP + p] = c0;
    }
    if (mycnt >= 2) {
        int ofs = atomicAdd(&lpos[w1], 1);
        int p = lbase[w1] + ofs;
        if (p < CAP) gbuf[(size_t)(w1 * 32 + b) * CAP + p] = c1;
    }
}

// K4: merged k2+k4 — per (which,b): bounds scan then exact r-th largest.
__global__ __launch_bounds__(256) void k4_thresh(
    const int* __restrict__ hist, const float* __restrict__ nfg_sum,
    const unsigned long long* __restrict__ gbuf, const int* __restrict__ gcnt,
    unsigned long long* __restrict__ thr)
{
    int wb = blockIdx.x;              // 0..63: which*32 + b
    int which = wb >> 5, b = wb & 31;
    int t = threadIdx.x;
    int mybin = hist[wb * NBINS + t];

    __shared__ int suf[256];
    __shared__ int sbb, srsel;
    suf[t] = mybin;
    __syncthreads();
    for (int off = 1; off < 256; off <<= 1) {
        int add = (t + off < 256) ? suf[t + off] : 0;
        __syncthreads();
        suf[t] += add;
        __syncthreads();
    }
    int total = suf[0];

    int sel;
    if (which == 0) {
        sel = total < 256 ? total : 256;
    } else {
        float nfg = nfg_sum[b];
        float cl  = 1024.f - fminf(nfg, 256.f);
        int cnt = (cl <= 0.f) ? 0 : (int)ceilf(cl);
        cnt = cnt > 1024 ? 1024 : cnt;
        sel = cnt < total ? cnt : total;
    }
    if (t == 0) {
        if (sel <= 0)          { sbb = -1; srsel = 0; }
        else if (sel >= total) { sbb = -2; srsel = 0; }
    }
    int cumAbove = suf[t] - mybin;
    if (sel > 0 && sel < total && cumAbove < sel && suf[t] >= sel) {
        sbb   = t;                        // unique boundary thread
        srsel = sel - cumAbove;           // 1-based rank within bin
    }
    __syncthreads();

    int bbv = sbb;
    if (bbv == -1) { if (t == 0) thr[wb] = ~0ULL; return; }  // select none
    if (bbv == -2) { if (t == 0) thr[wb] = 0ULL;  return; }  // select all masked
    int n = gcnt[wb]; n = n > CAP ? CAP : n;
    int r = srsel;
    const unsigned long long* buf = gbuf + (size_t)wb * CAP;
    for (int i = t; i < n; i += 256) {
        unsigned long long k = buf[i];
        int rank = 0;
        for (int j = 0; j < n; ++j) rank += (buf[j] > k) ? 1 : 0;
        if (rank == r - 1) thr[wb] = k;   // keys unique -> exactly one writer
    }
}

// K5: anchor write, in-place over rec. 4 independent uint4 loads per
// thread issued back-to-back (ILP=4) before any use; block = 4096 cells
// (batch-aligned), grid 2048.
__global__ __launch_bounds__(256, 4) void k5_anchor(
    unsigned* __restrict__ rec, const unsigned long long* __restrict__ thr)
{
    int tid  = threadIdx.x;
    int base = blockIdx.x * 4096;
    int b    = base >> 18;
    unsigned long long tf = thr[b], tb = thr[32 + b];

    int c0 = base + tid * 4;
    uint4 r0 = *reinterpret_cast<const uint4*>(rec + c0);
    uint4 r1 = *reinterpret_cast<const uint4*>(rec + c0 + 1024);
    uint4 r2 = *reinterpret_cast<const uint4*>(rec + c0 + 2048);
    uint4 r3 = *reinterpret_cast<const uint4*>(rec + c0 + 3072);

    #pragma unroll
    for (int q = 0; q < 4; ++q) {
        uint4 r = (q == 0) ? r0 : (q == 1) ? r1 : (q == 2) ? r2 : r3;
        int ib = c0 + q * 1024;
        float4 o;
        #pragma unroll
        for (int j = 0; j < 4; ++j) {
            unsigned rv = ((const unsigned*)&r)[j];
            unsigned flag = rv >> 30;
            float v = 0.f;
            if (flag) {
                unsigned ub  = rv & 0x3FFFFFFFu;
                unsigned inb = (unsigned)((ib + j) & (TT - 1));
                unsigned long long key =
                    ((unsigned long long)ub << 32) | (0xFFFFFFFFu - inb);
                v = (key >= ((flag == 1u) ? tf : tb)) ? 1.f : 0.f;
            }
            ((float*)&o)[j] = v;
        }
        *reinterpret_cast<float4*>(rec + ib) = o;
    }
}

extern "C" void kernel_launch(void* const* d_in, const int* in_sizes, int n_in,
                              void* d_out, int out_size, void* d_ws, size_t ws_size,
                              hipStream_t stream)
{
    const float* gt   = (const float*)d_in[0];
    const float* alli = (const float*)d_in[1];
    const float* ufg  = (const float*)d_in[2];
    const float* ubg  = (const float*)d_in[3];

    char* ws = (char*)d_ws;
    int*                 hist = (int*)(ws + OFF_HIST);
    float*               nfg  = (float*)(ws + OFF_NFG);
    int*                 gcnt = (int*)(ws + OFF_GCNT);
    unsigned long long*  thr  = (unsigned long long*)(ws + OFF_THR);
    unsigned long long*  gbuf = (unsigned long long*)(ws + OFF_GBUF);

    float* coords  = (float*)d_out;
    float* anchorF = coords + (size_t)3 * NCELL;
    unsigned* rec  = (unsigned*)anchorF;             // staging, overwritten by K5
    float* posv    = anchorF + NCELL;

    hipMemsetAsync(d_ws, 0, ZERO_BYTES, stream);

    dim3 blk(256);
    k1_main  <<<dim3(1024), blk, 0, stream>>>(gt, alli, ufg, ubg, coords, posv, rec, hist, nfg);
    k3_gather<<<dim3(1024), blk, 0, stream>>>(rec, hist, nfg, gbuf, gcnt);
    k4_thresh<<<dim3(64),   blk, 0, stream>>>(hist, nfg, gbuf, gcnt, thr);
    k5_anchor<<<dim3(2048), blk, 0, stream>>>(rec, thr);
}